// Round 7
// baseline (331.880 us; speedup 1.0000x reference)
//
#include <hip/hip_runtime.h>
#include <cstdint>

typedef __bf16 bf16;
typedef __bf16 bf16x8 __attribute__((ext_vector_type(8)));
typedef float  f32x4  __attribute__((ext_vector_type(4)));

#define BARRIER()    asm volatile("s_barrier" ::: "memory")
#define WAIT_LGKM0() asm volatile("s_waitcnt lgkmcnt(0)" ::: "memory")
#define WAIT_VM(n)   asm volatile("s_waitcnt vmcnt(" #n ")" ::: "memory")

// ---------------------------------------------------------------------------
// Fused prep kernel: hf-GEMM (320 blocks) | hg-GEMM (90) | W2 transpose (640).
// ---------------------------------------------------------------------------
__device__ void gemm_small_body(
    const float* __restrict__ A, const float* __restrict__ Bm,
    const float* __restrict__ bias, bf16* __restrict__ Cout,
    int M, int N, int K, int bx, int by)
{
    __shared__ float As[64][20];
    __shared__ float Bs[16][68];
    const int tid = threadIdx.x;
    const int m0 = bx * 64, n0 = by * 64;
    const int tx = tid & 15, ty = tid >> 4;
    const int arow = tid >> 2, ak = (tid & 3) << 2;
    const int bk = tid >> 4, bc = (tid & 15) << 2;
    const bool avalid = (m0 + arow) < M;
    float acc[4][4] = {};

    for (int k0 = 0; k0 < K; k0 += 16) {
        float4 av = make_float4(0.f, 0.f, 0.f, 0.f);
        if (avalid) av = *(const float4*)&A[(size_t)(m0 + arow) * K + k0 + ak];
        float4 bv = *(const float4*)&Bm[(size_t)(k0 + bk) * N + n0 + bc];
        __syncthreads();
        *(float4*)&As[arow][ak] = av;
        *(float4*)&Bs[bk][bc] = bv;
        __syncthreads();
#pragma unroll
        for (int k = 0; k < 16; ++k) {
            float a[4], b[4];
#pragma unroll
            for (int i = 0; i < 4; ++i) a[i] = As[ty * 4 + i][k];
#pragma unroll
            for (int j = 0; j < 4; ++j) b[j] = Bs[k][tx * 4 + j];
#pragma unroll
            for (int i = 0; i < 4; ++i)
#pragma unroll
                for (int j = 0; j < 4; ++j) acc[i][j] += a[i] * b[j];
        }
    }
#pragma unroll
    for (int i = 0; i < 4; ++i) {
        int row = m0 + ty * 4 + i;
        if (row >= M) continue;
#pragma unroll
        for (int j = 0; j < 4; ++j) {
            int col = n0 + tx * 4 + j;
            float v = acc[i][j] + (bias ? bias[col] : 0.f);
            Cout[(size_t)row * N + col] = (bf16)v;
        }
    }
}

__device__ void w2t_body(const float* __restrict__ W2, bf16* __restrict__ W2T,
                         int bx, int by)
{
    __shared__ float t[32][33];
    const int tx = threadIdx.x & 31, ty = threadIdx.x >> 5;  // 32 x 8
    const int n0 = bx * 32, k0 = by * 32;
#pragma unroll
    for (int i = 0; i < 4; ++i)
        t[ty + i * 8][tx] = W2[(size_t)(k0 + ty + i * 8) * 1024 + n0 + tx];
    __syncthreads();
#pragma unroll
    for (int i = 0; i < 4; ++i)
        W2T[(size_t)(n0 + ty + i * 8) * 640 + k0 + tx] = (bf16)t[tx][ty + i * 8];
}

__global__ __launch_bounds__(256) void prep(
    const float* __restrict__ f, const float* __restrict__ g,
    const float* __restrict__ W1, const float* __restrict__ b1,
    const float* __restrict__ W2,
    bf16* __restrict__ hf, bf16* __restrict__ hgb, bf16* __restrict__ W2T)
{
    const int bid = blockIdx.x;
    if (bid < 320) {
        gemm_small_body(f, W1, nullptr, hf, 2048, 640, 1024, bid % 32, bid / 32);
    } else if (bid < 410) {
        int b = bid - 320;
        gemm_small_body(g, W1 + 1024 * 640, b1, hgb, 520, 640, 320, b % 9, b / 9);
    } else {
        int b = bid - 410;
        w2t_body(W2, W2T, b % 32, b / 32);
    }
}

// ---------------------------------------------------------------------------
// Stage 2: fused joint GEMM, 3 blocks/CU, Bs double-buffered, counted vmcnt.
// BM=128 BN=128 BK=64, 256 thr = 4 waves (2Mx2N), wave tile 64x64 (64 AGPR).
// LDS 48 KB: As[128x64] + Bs[2][128x64], XOR-swizzle 16B chunks.
// Per tile t:
//   genA(t)    : consume A-source regs (drains loads(t)) -> relu -> ds_write
//   loadA(t+1) : refill regs                                   [+8 vmem]
//   stageB(t+1): DMA into BACK Bs buffer (full-tile flight)    [+4 vmem]
//   WAIT_VM(12): drains exactly DMA(t) (front Bs ready)
//   lgkm0; BARRIER; mfma on front buffers w/ setprio; BARRIER
// ---------------------------------------------------------------------------
__global__ __launch_bounds__(256, 3) void joint_main(
    const bf16* __restrict__ hf, const bf16* __restrict__ hgb,
    const bf16* __restrict__ W2T, const float* __restrict__ b2,
    float* __restrict__ out)
{
    __shared__ bf16 As[128 * 64];        // 16 KB
    __shared__ bf16 Bs[2][128 * 64];     // 32 KB
    const int tid = threadIdx.x;
    const int n0 = blockIdx.x * 128;
    const int m0 = blockIdx.y * 128;

    // --- A-generation mapping: thread -> (row r, k-half of 32 elems) ---
    const int r  = tid >> 1;               // 0..127
    const int kh = (tid & 1) << 5;         // 0 or 32 (bf16 elems)
    const int c0 = (tid & 1) << 2;         // first of 4 16B-chunks (0 or 4)
    int aoff[4];
#pragma unroll
    for (int c = 0; c < 4; ++c)
        aoff[c] = r * 64 + (((c0 + c) ^ (r & 7)) << 3);

    const int m  = m0 + r;
    const int bt = m / 65;
    const int uu = m - bt * 65;
    const int bb = bt >> 8;
    const bf16* hfp = hf  + (size_t)bt * 640 + kh;
    const bf16* hgp = hgb + (size_t)(bb * 65 + uu) * 640 + kh;

    // --- wave mapping: 2 (M) x 2 (N), wave tile 64x64 ---
    const int wid = tid >> 6, lane = tid & 63;
    const int wr = wid >> 1, wc = wid & 1;
    const int lg = lane >> 4, l15 = lane & 15;

    f32x4 acc[4][4] = {};
    bf16x8 F[4], G[4];                      // A-source regs (single set)

    auto loadA = [&](int k0) {
#pragma unroll
        for (int i = 0; i < 4; ++i) {
            F[i] = *(const bf16x8*)(hfp + k0 + i * 8);
            G[i] = *(const bf16x8*)(hgp + k0 + i * 8);
        }
    };
    auto stageB = [&](int buf, int k0) {
        const char* w2b = (const char*)W2T + (size_t)k0 * 2;
#pragma unroll
        for (int call = 0; call < 4; ++call) {
            int chunk = call * 256 + tid;          // 0..1023
            int brow = chunk >> 3, c = chunk & 7;
            const char* src = w2b + (size_t)(n0 + brow) * 1280
                                  + ((c ^ (brow & 7)) << 4);
            __builtin_amdgcn_global_load_lds(
                (const __attribute__((address_space(1))) uint32_t*)src,
                (__attribute__((address_space(3))) uint32_t*)&Bs[buf][chunk << 3],
                16, 0, 0);
        }
    };
    auto genA = [&]() {
#pragma unroll
        for (int c = 0; c < 4; ++c) {
            bf16x8 O;
#pragma unroll
            for (int i = 0; i < 8; ++i) {
                float s = (float)F[c][i] + (float)G[c][i];
                O[i] = (bf16)fmaxf(s, 0.f);
            }
            *(bf16x8*)&As[aoff[c]] = O;
        }
    };
    auto mfmaPhase = [&](int buf) {
        __builtin_amdgcn_s_setprio(1);
#pragma unroll
        for (int kk = 0; kk < 2; ++kk) {
            const int clog = (kk << 2) + lg;
            bf16x8 bfr[4], afr[4];
#pragma unroll
            for (int ni = 0; ni < 4; ++ni) {
                int row = wc * 64 + ni * 16 + l15;
                bfr[ni] = *(const bf16x8*)&Bs[buf][row * 64 + ((clog ^ (row & 7)) << 3)];
            }
#pragma unroll
            for (int mi = 0; mi < 4; ++mi) {
                int row = wr * 64 + mi * 16 + l15;
                afr[mi] = *(const bf16x8*)&As[row * 64 + ((clog ^ (row & 7)) << 3)];
            }
#pragma unroll
            for (int mi = 0; mi < 4; ++mi)
#pragma unroll
                for (int ni = 0; ni < 4; ++ni)
                    acc[mi][ni] = __builtin_amdgcn_mfma_f32_16x16x32_bf16(
                        afr[mi], bfr[ni], acc[mi][ni], 0, 0, 0);
        }
        __builtin_amdgcn_s_setprio(0);
    };

    // ---- prologue: loads(0) x8 then DMA(0) x4 into Bs[0] ----
    loadA(0);
    stageB(0, 0);

#pragma unroll 1
    for (int t = 0; t < 10; ++t) {
        const int bufB = t & 1;
        genA();                              // drains loads(t) via compiler vmcnt
        if (t < 9) {
            loadA((t + 1) * 64);             // +8 vmem, full-tile flight
            stageB(bufB ^ 1, (t + 1) * 64);  // +4 vmem into back buffer
            WAIT_VM(12);                     // retires exactly DMA(t)
        } else {
            WAIT_VM(0);
        }
        WAIT_LGKM0();                        // As ds_writes visible
        BARRIER();
        mfmaPhase(bufB);
        BARRIER();
    }

    // ---- epilogue: +b2, fp32 stores ----
    float bv[4];
#pragma unroll
    for (int ni = 0; ni < 4; ++ni) bv[ni] = b2[n0 + wc * 64 + ni * 16 + l15];
#pragma unroll
    for (int mi = 0; mi < 4; ++mi) {
#pragma unroll
        for (int ni = 0; ni < 4; ++ni) {
            int col = n0 + wc * 64 + ni * 16 + l15;
#pragma unroll
            for (int j = 0; j < 4; ++j) {
                int row = m0 + wr * 64 + mi * 16 + lg * 4 + j;
                out[(size_t)row * 1024 + col] = acc[mi][ni][j] + bv[ni];
            }
        }
    }
}

// ---------------------------------------------------------------------------
extern "C" void kernel_launch(void* const* d_in, const int* in_sizes, int n_in,
                              void* d_out, int out_size, void* d_ws, size_t ws_size,
                              hipStream_t stream)
{
    const float* f  = (const float*)d_in[0];   // (8,256,1024)
    const float* g  = (const float*)d_in[1];   // (8,65,320)
    const float* W1 = (const float*)d_in[2];   // (1344,640)
    const float* b1 = (const float*)d_in[3];   // (640)
    const float* W2 = (const float*)d_in[4];   // (640,1024)
    const float* b2 = (const float*)d_in[5];   // (1024)
    float* out = (float*)d_out;                // (8,256,65,1024)

    bf16* hf  = (bf16*)d_ws;                   // 2048*640
    bf16* hgb = hf + 2048 * 640;               // 520*640 (g@W1g + b1)
    bf16* W2T = hgb + 520 * 640;               // 1024*640

    prep<<<1050, 256, 0, stream>>>(f, g, W1, b1, W2, hf, hgb, W2T);
    joint_main<<<dim3(8, 1040), 256, 0, stream>>>(hf, hgb, W2T, b2, out);
}